// Round 23
// baseline (240.822 us; speedup 1.0000x reference)
//
#include <hip/hip_runtime.h>
#include <hip/hip_bf16.h>

// ---- types ----
typedef __attribute__((ext_vector_type(8))) short v8s;   // 8 x bf16
typedef __attribute__((ext_vector_type(4))) float v4f;
typedef __attribute__((ext_vector_type(16))) float v16f; // 32x32 MFMA C/D
typedef __attribute__((ext_vector_type(4))) unsigned v4u;

#define S_LEN 2048
#define NB 4
#define NH 16
#define LOG2E 1.4426950408889634f
// Mask constant: 1.3125 * 2^40 — EXACTLY representable in bf16 AND fp32.
#define CMASK 1443109011456.0f
#define DEFER_THR 11.55f                // ~8 * log2(e)  (T13)

__device__ __forceinline__ short f2bf(float f) {
    __hip_bfloat16 h = __float2bfloat16(f);
    union { __hip_bfloat16 h; short s; } u; u.h = h; return u.s;
}
__device__ __forceinline__ float bf2f(short s) {
    union { unsigned u; float f; } u; u.u = ((unsigned)(unsigned short)s) << 16;
    return u.f;
}

__device__ __forceinline__ unsigned cvtpk(float lo, float hi) {
    unsigned r;
    asm("v_cvt_pk_bf16_f32 %0, %1, %2" : "=v"(r) : "v"(lo), "v"(hi));
    return r;
}

// XOR swizzle for [R][128B] LDS tiles (read side); write side realized by
// pre-swizzling the gload_lds SOURCE chunk (rule #21, R8-verified involution).
__device__ __forceinline__ int swz(int row, int col) {
    return (row * 128 + col) ^ ((row & 7) << 4);
}

__device__ __forceinline__ void async16(void* lds, const void* g) {
    __builtin_amdgcn_global_load_lds(
        (const __attribute__((address_space(1))) unsigned int*)g,
        (__attribute__((address_space(3))) unsigned int*)lds, 16, 0, 0);
}

#define MFMA16(a, b, c) __builtin_amdgcn_mfma_f32_16x16x32_bf16((a), (b), (c), 0, 0, 0)
#define MFMA32(a, b, c) __builtin_amdgcn_mfma_f32_32x32x16_bf16((a), (b), (c), 0, 0, 0)

// ------- fused convert fp32->bf16 (q,k,v) + zero-fill of out (y=3) ---------
__global__ __launch_bounds__(256) void convert_all(const float* __restrict__ q,
                                                   const float* __restrict__ k,
                                                   const float* __restrict__ v,
                                                   short* __restrict__ Xq,
                                                   short* __restrict__ Xk,
                                                   short* __restrict__ Xv,
                                                   float* __restrict__ outz) {
    if (blockIdx.y == 3) {                    // zero-fill out (dead rows = 0)
        size_t i = ((size_t)blockIdx.x * 256 + threadIdx.x) * 8;
        float4 z4 = {0.f, 0.f, 0.f, 0.f};
        *(float4*)(outz + i) = z4;
        *(float4*)(outz + i + 4) = z4;
        return;
    }
    const float* in = (blockIdx.y == 0) ? q : (blockIdx.y == 1) ? k : v;
    short* out = (blockIdx.y == 0) ? Xq : (blockIdx.y == 1) ? Xk : Xv;
    size_t i = ((size_t)blockIdx.x * 256 + threadIdx.x) * 8;
    float4 a = *(const float4*)(in + i);
    float4 b = *(const float4*)(in + i + 4);
    v8s o;
    o[0] = f2bf(a.x); o[1] = f2bf(a.y); o[2] = f2bf(a.z); o[3] = f2bf(a.w);
    o[4] = f2bf(b.x); o[5] = f2bf(b.y); o[6] = f2bf(b.z); o[7] = f2bf(b.w);
    *(v8s*)(out + i) = o;
}

// ---------------- penalty column: pen[b][s] = vm ? 0 : -CMASK (bf16) -------
__global__ __launch_bounds__(256) void build_pen(const int* __restrict__ vm,
                                                 short* __restrict__ penC) {
    int i = blockIdx.x * 256 + threadIdx.x;   // 8192 total
    penC[i] = vm[i] ? (short)0 : f2bf(-CMASK);
}

// ------------- q_mask compaction: idx[b][j] = j-th live row, nq[b] ---------
__global__ __launch_bounds__(256) void compact_qmask(const int* __restrict__ qm,
                                                     int* __restrict__ idx,
                                                     int* __restrict__ nq) {
    const int b = blockIdx.x;
    const int* m = qm + b * S_LEN;
    int* ib = idx + b * S_LEN;
    __shared__ int cnt[256];
    const int t = threadIdx.x;
    int loc[8], c = 0;
#pragma unroll
    for (int i = 0; i < 8; ++i) { int s = t * 8 + i; if (m[s]) loc[c++] = s; }
    cnt[t] = c;
    __syncthreads();
    for (int d = 1; d < 256; d <<= 1) {       // Hillis-Steele inclusive scan
        int v = (t >= d) ? cnt[t - d] : 0;
        __syncthreads();
        cnt[t] += v;
        __syncthreads();
    }
    int off = cnt[t] - c;                     // exclusive prefix
    for (int i = 0; i < c; ++i) ib[off + i] = loc[i];
    if (t == 255) nq[b] = cnt[255];
}

// ---------------- fused W[K][N] fp32 -> WT[N][K] bf16 (4 weights) ----------
__global__ __launch_bounds__(256) void transpose_all(const float* __restrict__ Wq,
                                                     const float* __restrict__ Wk,
                                                     const float* __restrict__ Wv,
                                                     const float* __restrict__ Wo,
                                                     short* __restrict__ WTq,
                                                     short* __restrict__ WTk,
                                                     short* __restrict__ WTv,
                                                     short* __restrict__ WTo) {
    const int z = blockIdx.z;
    const float* W = (z == 0) ? Wq : (z == 1) ? Wk : (z == 2) ? Wv : Wo;
    short* WT = (z == 0) ? WTq : (z == 1) ? WTk : (z == 2) ? WTv : WTo;
    __shared__ float tile[32][33];
    int k0 = blockIdx.x * 32, n0 = blockIdx.y * 32;
    int tx = threadIdx.x & 31, ty = threadIdx.x >> 5;  // ty 0..7
#pragma unroll
    for (int i = 0; i < 4; ++i)
        tile[ty + i * 8][tx] = W[(size_t)(k0 + ty + i * 8) * 1024 + n0 + tx];
    __syncthreads();
#pragma unroll
    for (int i = 0; i < 4; ++i)
        WT[(size_t)(n0 + ty + i * 8) * 1024 + k0 + tx] = f2bf(tile[tx][ty + i * 8]);
}

// ---------------- unified projection GEMM: z=0 K, z=1 V, z=2 Q-compacted ---
// XCD map (T1) + LDS swizzle (G4) + fragment-major K/V (R18) + dbuf/counted
// vmcnt (R19) + 8-wave blocks (R22). Frozen.
__global__ __launch_bounds__(512)
void proj_all(const short* __restrict__ Xk, const short* __restrict__ Xv,
              const short* __restrict__ Xq,
              const short* __restrict__ WTk, const short* __restrict__ WTv,
              const short* __restrict__ WTq,
              const float* __restrict__ bk, const float* __restrict__ bv,
              const float* __restrict__ bq,
              const int* __restrict__ idx, const int* __restrict__ nq,
              short* __restrict__ KF, short* __restrict__ VF,
              short* __restrict__ QW) {
    __shared__ short As[2][128 * 64];
    __shared__ short Bs[2][128 * 64];
    const int tid = threadIdx.x;
    const int l = tid & 63, w = tid >> 6;       // w in 0..7
    const int g = l >> 4, ql = l & 15;
    const int z = blockIdx.z;
    const int bid = blockIdx.x;
    const int y = (bid & 7) + 8 * (bid >> 6);   // M-tile (XCD-pinned)
    const int n0 = ((bid >> 3) & 7) * 128;      // N-tile (cycles fastest)
    const int wr = w >> 2, wc = w & 3;          // 2x4 wave grid

    int b = 0, m0 = y * 128, m0c = 0, nqv = 0;
    const int* idxb = nullptr;
    if (z == 2) {
        if (y >= 36) return;
        b = y / 9; m0c = (y % 9) * 128;
        nqv = nq[b];
        if (m0c >= nqv) return;
        idxb = idx + b * S_LEN;
    }
    const short* A  = (z == 0) ? Xk : (z == 1) ? Xv : Xq;
    const short* BT = (z == 0) ? WTk : (z == 1) ? WTv : WTq;
    const float* bias = (z == 0) ? bk : (z == 1) ? bv : bq;

    int arow[2];
#pragma unroll
    for (int i = 0; i < 2; ++i) {
        int row = (i * 512 + tid) >> 3;
        if (z == 2) {
            int jc = m0c + row;
            arow[i] = b * S_LEN + idxb[(jc < nqv) ? jc : (nqv - 1)];
        } else {
            arow[i] = m0 + row;
        }
    }
    const int c8 = (((l & 7) ^ (l >> 3))) * 8;

    v4f acc[4][2] = {};

    auto stage = [&](int kt, int buf) {
        const int kk = kt * 64;
#pragma unroll
        for (int i = 0; i < 2; ++i) {
            int ci = i * 512 + tid;
            async16((char*)As[buf] + (size_t)ci * 16,
                    A + (size_t)arow[i] * 1024 + kk + c8);
            async16((char*)Bs[buf] + (size_t)ci * 16,
                    BT + (size_t)(n0 + (ci >> 3)) * 1024 + kk + c8);
        }
    };

    stage(0, 0);
    for (int kt = 0; kt < 16; ++kt) {
        __builtin_amdgcn_s_barrier();
        __builtin_amdgcn_sched_barrier(0);
        if (kt + 1 < 16) {
            stage(kt + 1, (kt + 1) & 1);
            asm volatile("s_waitcnt vmcnt(4)" ::: "memory");
        } else {
            asm volatile("s_waitcnt vmcnt(0)" ::: "memory");
        }
        __builtin_amdgcn_sched_barrier(0);
        __builtin_amdgcn_s_barrier();
        __builtin_amdgcn_sched_barrier(0);
        const short* Ab = As[kt & 1];
        const short* Bb = Bs[kt & 1];
#pragma unroll
        for (int ks = 0; ks < 2; ++ks) {
            v8s af[4], bfr[2];
#pragma unroll
            for (int mt = 0; mt < 4; ++mt)
                af[mt] = *(const v8s*)((char*)Ab +
                          swz(wr * 64 + mt * 16 + ql, ks * 64 + g * 16));
#pragma unroll
            for (int nt = 0; nt < 2; ++nt)
                bfr[nt] = *(const v8s*)((char*)Bb +
                          swz(wc * 32 + nt * 16 + ql, ks * 64 + g * 16));
#pragma unroll
            for (int mt = 0; mt < 4; ++mt)
#pragma unroll
                for (int nt = 0; nt < 2; ++nt)
                    acc[mt][nt] = MFMA16(af[mt], bfr[nt], acc[mt][nt]);
        }
    }

#pragma unroll
    for (int nt = 0; nt < 2; ++nt) {
        int col = n0 + wc * 32 + nt * 16 + ql;
        float bval = bias[col];
        int hh = col >> 6, dd = col & 63;
#pragma unroll
        for (int mt = 0; mt < 4; ++mt) {
#pragma unroll
            for (int r = 0; r < 4; ++r) {
                int lrow = wr * 64 + mt * 16 + g * 4 + r;
                float vv = acc[mt][nt][r] + bval;
                if (z == 0) {
                    int gm = m0 + lrow;
                    int bb = gm >> 11, ss = gm & 2047;
                    size_t base = (size_t)(bb * NH + hh) * 131072
                                + (size_t)(ss >> 6) * 4096
                                + (dd >> 4) * 1024 + (ss & 63) * 16
                                + ((dd >> 3) & 1) * 8 + (dd & 7);
                    KF[base] = f2bf(vv);
                } else if (z == 1) {
                    int gm = m0 + lrow;
                    int bb = gm >> 11, ss = gm & 2047;
                    int wkp = ss & 63;
                    size_t base = (size_t)(bb * NH + hh) * 131072
                                + (size_t)(ss >> 6) * 4096
                                + (wkp >> 4) * 1024 + dd * 16
                                + ((wkp >> 3) & 1) * 8 + (wkp & 7);
                    VF[base] = f2bf(vv);
                } else {
                    int jc = m0c + lrow;                 // compacted row
                    vv *= 0.125f * LOG2E;
                    QW[((size_t)(b * NH + hh) * S_LEN + jc) * 64 + dd] = f2bf(vv);
                }
            }
        }
    }
}

// ---------------- flash attention: streaming fragment-major + split-K ------
// R22 counters: Occ 9.8% with all 4096 waves resident = tail signature;
// makespan == longest wave's 32-tile chain. Both prior split-K failures had
// confounds now removed (R12: not chain-bound; R17: L2-BW-bound, halved by
// fragment-major). Chunks NT>8 run as 2 pieces (chain 32 -> 16); partials
// merge exactly in attn_combine. Unsplit keep direct write + rescue (split
// rows have >=448 valid keys -> all-masked prob 2^-448).
__global__ __launch_bounds__(64)
void attn_kernel(const short* __restrict__ QW, const short* __restrict__ KF,
                 const short* __restrict__ VF, const short* __restrict__ penC,
                 const int* __restrict__ idx, const int* __restrict__ nq,
                 short* __restrict__ O,
                 float* __restrict__ mP, float* __restrict__ lP,
                 short* __restrict__ accP) {
    const int l = threadIdx.x;                // 1 wave
    const int lq = l & 31, hi = l >> 5;
    const int bh = blockIdx.x;
    const int y = blockIdx.y;
    const int piece = y & 1;
    const int chunk = 63 - (y >> 1);          // heavy chunks dispatch first
    const int b = bh >> 4, hd = bh & 15;

    const int nqv = nq[b];
    const int cy = chunk * 32;                // compacted base row (32/wave)
    if (cy >= nqv) return;                    // dead chunk retires instantly

    const short* Qp = QW + (size_t)bh * S_LEN * 64;
    const short* Kp = KF + (size_t)bh * 131072;
    const short* Vp = VF + (size_t)bh * 131072;
    const short* pp = penC + b * S_LEN;
    const int* idxb = idx + b * S_LEN;

    const int j = cy + lq;
    const int jj = (j < nqv) ? j : (nqv - 1);
    const int q_glob = idxb[jj];
    const int qmin = __builtin_amdgcn_readfirstlane(q_glob);

    int lastj = cy + 31; if (lastj > nqv - 1) lastj = nqv - 1;
    const int NT = (idxb[lastj] >> 6) + 1;
    const bool split = (NT > 8);
    if (!split && piece) return;              // light chunk: piece 1 idle
    const int H = NT >> 1;
    const int t0 = split ? (piece ? H : 0) : 0;
    const int t1 = split ? (piece ? NT : H) : NT;

    // Q fragments from COMPACTED QW
    v8s qf[4];
#pragma unroll
    for (int ks = 0; ks < 4; ++ks)
        qf[ks] = *(const v8s*)(Qp + (size_t)jj * 64 + ks * 16 + hi * 8);
    v8s qf4 = {};
    qf4[0] = hi ? (short)0 : (short)0x3F80;   // bf16(1.0) at virtual k=64

    v16f accO[2] = {};
    float m_run = -INFINITY, l_run = 0.f;

    auto tile = [&](int kt, bool causal) {
        const int k0 = kt * 64;
        const short* Kt = Kp + (size_t)kt * 4096;
        const short* Vt = Vp + (size_t)kt * 4096;
        short p0 = pp[k0 + lq], p1 = pp[k0 + lq + 32];

        // K fragments: 1KB contiguous per load (fragment-major layout)
        v8s kf0[4], kf1[4];
#pragma unroll
        for (int ks = 0; ks < 4; ++ks) {
            kf0[ks] = *(const v8s*)(Kt + ks * 1024 + lq * 16 + hi * 8);
            kf1[ks] = *(const v8s*)(Kt + ks * 1024 + (lq + 32) * 16 + hi * 8);
        }
        v16f acc0 = {}, acc1 = {};
        __builtin_amdgcn_s_setprio(1);
#pragma unroll
        for (int ks = 0; ks < 4; ++ks) {
            acc0 = MFMA32(kf0[ks], qf[ks], acc0);
            acc1 = MFMA32(kf1[ks], qf[ks], acc1);
        }
        // 5th slice: v_mask penalty column (hi=0 lanes carry pen at k=64)
        v8s k4a = {}, k4b = {};
        k4a[0] = hi ? (short)0 : p0;
        k4b[0] = hi ? (short)0 : p1;
        acc0 = MFMA32(k4a, qf4, acc0);
        acc1 = MFMA32(k4b, qf4, acc1);
        __builtin_amdgcn_s_setprio(0);

        float s[32];
#pragma unroll
        for (int jn = 0; jn < 16; ++jn) { s[jn] = acc0[jn]; s[16 + jn] = acc1[jn]; }
        if (causal) {
#pragma unroll
            for (int t = 0; t < 2; ++t)
#pragma unroll
                for (int jn = 0; jn < 16; ++jn) {
                    int kp = k0 + t * 32 + (jn & 3) + 8 * (jn >> 2) + 4 * hi;
                    if (kp > q_glob) s[t * 16 + jn] -= CMASK;
                }
        }
        // tree max (depth 5)
        float t8[8];
#pragma unroll
        for (int i = 0; i < 8; ++i)
            t8[i] = fmaxf(fmaxf(s[i], s[i + 8]), fmaxf(s[i + 16], s[i + 24]));
#pragma unroll
        for (int i = 0; i < 4; ++i) t8[i] = fmaxf(t8[i], t8[i + 4]);
        float tmax = fmaxf(fmaxf(t8[0], t8[1]), fmaxf(t8[2], t8[3]));
        tmax = fmaxf(tmax, __shfl_xor(tmax, 32, 64));   // cross-half

        // T13 defer-max
        if (__any(tmax > m_run + DEFER_THR)) {
            float mnew = fmaxf(m_run, tmax);
            float scale = exp2f(m_run - mnew);
            m_run = mnew;
            l_run *= scale;
#pragma unroll
            for (int jn = 0; jn < 16; ++jn) {
                float sc = __shfl(scale, (jn & 3) + 8 * (jn >> 2) + 4 * hi, 64);
                accO[0][jn] *= sc;
                accO[1][jn] *= sc;
            }
        }
#pragma unroll
        for (int i = 0; i < 32; ++i) s[i] = exp2f(s[i] - m_run);
        // tree sum
        float u8[8];
#pragma unroll
        for (int i = 0; i < 8; ++i)
            u8[i] = (s[i] + s[i + 8]) + (s[i + 16] + s[i + 24]);
#pragma unroll
        for (int i = 0; i < 4; ++i) u8[i] += u8[i + 4];
        float psum = (u8[0] + u8[1]) + (u8[2] + u8[3]);
        psum += __shfl_xor(psum, 32, 64);               // cross-half
        l_run += psum;

        // V fragments: 1KB contiguous per load (fragment-major layout)
        v8s vf0[4], vf1[4];
#pragma unroll
        for (int ks = 0; ks < 4; ++ks) {
            vf0[ks] = *(const v8s*)(Vt + ks * 1024 + lq * 16 + hi * 8);
            vf1[ks] = *(const v8s*)(Vt + ks * 1024 + (lq + 32) * 16 + hi * 8);
        }

        // P -> PV A-operand in registers (cvt_pk + permlane32_swap; SSA-distinct)
        v8s PA[4];
#pragma unroll
        for (int t = 0; t < 2; ++t)
#pragma unroll
            for (int sf = 0; sf < 2; ++sf) {
                int base = t * 16 + sf * 8;
                unsigned x0 = cvtpk(s[base + 0], s[base + 1]);
                unsigned x1 = cvtpk(s[base + 2], s[base + 3]);
                unsigned y0 = cvtpk(s[base + 4], s[base + 5]);
                unsigned y1 = cvtpk(s[base + 6], s[base + 7]);
                asm volatile("v_permlane32_swap_b32 %0, %1" : "+v"(x0), "+v"(y0));
                asm volatile("v_permlane32_swap_b32 %0, %1" : "+v"(x1), "+v"(y1));
                v4u wv; wv[0] = x0; wv[1] = x1; wv[2] = y0; wv[3] = y1;
                union { v4u u; v8s s8; } cvt; cvt.u = wv;
                PA[t * 2 + sf] = cvt.s8;
            }

        __builtin_amdgcn_s_setprio(1);
#pragma unroll
        for (int ks = 0; ks < 4; ++ks) {
            accO[0] = MFMA32(PA[ks], vf0[ks], accO[0]);
            accO[1] = MFMA32(PA[ks], vf1[ks], accO[1]);
        }
        __builtin_amdgcn_s_setprio(0);
    };

    // main loop over this piece's K-range — no barriers, compiler-pipelined
    for (int kt = t0; kt < t1; ++kt)
        tile(kt, kt * 64 + 63 > qmin);

    if (split) {
        // write partials (combine merges exactly)
        const int pidx = (bh * 64 + chunk) * 2 + piece;
        if (hi == 0) {
            mP[(size_t)pidx * 32 + lq] = m_run;
            lP[(size_t)pidx * 32 + lq] = l_run;
        }
        short* aPp = accP + (size_t)pidx * 2048;
#pragma unroll
        for (int jn = 0; jn < 16; ++jn) {
            int rowq = (jn & 3) + 8 * (jn >> 2) + 4 * hi;
            aPp[rowq * 64 + lq]      = f2bf(accO[0][jn]);
            aPp[rowq * 64 + 32 + lq] = f2bf(accO[1][jn]);
        }
        return;
    }

    // Rescue (unsplit only): rows whose causal-valid keys are ALL masked tie
    // with future keys at exactly -CMASK (fp32 reference semantics).
    int kt = t1;
    while (kt < 32 && __any(m_run < -1e11f)) {
        tile(kt, true);
        ++kt;
    }

    // direct epilogue: write Ob at COMPACTED row
    float inv = 1.0f / l_run;
#pragma unroll
    for (int jn = 0; jn < 16; ++jn) {
        int rowq = (jn & 3) + 8 * (jn >> 2) + 4 * hi;
        float iv = __shfl(inv, rowq, 64);
        int jrow = cy + rowq;
        if (jrow < nqv) {
            size_t base = (size_t)(b * S_LEN + jrow) * 1024 + hd * 64 + lq;
            O[base]      = f2bf(accO[0][jn] * iv);
            O[base + 32] = f2bf(accO[1][jn] * iv);
        }
    }
}

// ---------------- split-K combine: merge 2 partials, normalize, write Ob ---
__global__ __launch_bounds__(64)
void attn_combine(const float* __restrict__ mP, const float* __restrict__ lP,
                  const short* __restrict__ accP, const int* __restrict__ idx,
                  const int* __restrict__ nq, short* __restrict__ O) {
    const int bh = blockIdx.x, chunk = blockIdx.y;
    const int b = bh >> 4, hd = bh & 15;
    const int nqv = nq[b];
    const int cy = chunk * 32;
    if (cy >= nqv) return;
    const int* idxb = idx + b * S_LEN;
    int lastj = cy + 31; if (lastj > nqv - 1) lastj = nqv - 1;
    const int NT = (idxb[lastj] >> 6) + 1;
    if (NT <= 8) return;                      // unsplit chunk: direct-written

    const int lane = threadIdx.x;             // d within head (0..63)
    const int p0 = (bh * 64 + chunk) * 2;
    const float* m0 = mP + (size_t)p0 * 32;  const float* m1 = m0 + 32;
    const float* l0 = lP + (size_t)p0 * 32;  const float* l1 = l0 + 32;
    const short* a0 = accP + (size_t)p0 * 2048;
    const short* a1 = a0 + 2048;

    for (int r = 0; r < 32; ++r) {
        int jrow = cy + r;
        if (jrow >= nqv) break;
        float ma = m0[r], mb = m1[r];
        float m = fmaxf(ma, mb);
        float s0 = exp2f(ma - m), s1 = exp2f(mb - m);
        float lsum = l0[r] * s0 + l1[r] * s1;
        float o = (bf2f(a0[r * 64 + lane]) * s0 + bf2f(a1[r * 64 + lane]) * s1)
                  / lsum;
        O[(size_t)(b * S_LEN + jrow) * 1024 + hd * 64 + lane] = f2bf(o);
    }
}

// ---------------- output projection, q-compacted (scatter + bias) ----------
// Same XCD map + dbuf/counted-vmcnt; 8-wave blocks (R22). Frozen.
__global__ __launch_bounds__(512)
void out_gemm_c(const short* __restrict__ A, const short* __restrict__ BT,
                const float* __restrict__ bias, const int* __restrict__ idx,
                const int* __restrict__ nq, float* __restrict__ out) {
    __shared__ short As[2][128 * 64];
    __shared__ short Bs[2][128 * 64];
    const int tid = threadIdx.x;
    const int l = tid & 63, w = tid >> 6;       // w in 0..7
    const int g = l >> 4, ql = l & 15;
    const int bid = blockIdx.x;
    const int y = (bid & 7) + 8 * (bid >> 6);   // M-tile (XCD-pinned)
    if (y >= 36) return;
    const int n0 = ((bid >> 3) & 7) * 128;      // N-tile (cycles fastest)
    const int b = y / 9;
    const int m0c = (y % 9) * 128;
    const int nqv = nq[b];
    if (m0c >= nqv) return;
    const int* idxb = idx + b * S_LEN;
    const int wr = w >> 2, wc = w & 3;          // 2x4 wave grid
    const int c8 = (((l & 7) ^ (l >> 3))) * 8;  // pre-swizzled source chunk

    v4f acc[4][2] = {};

    auto stage = [&](int kt, int buf) {
        const int kk = kt * 64;
#pragma unroll
        for (int i = 0; i < 2; ++i) {
            int ci = i * 512 + tid;
            int row = ci >> 3;
            async16((char*)As[buf] + (size_t)ci * 16,
                    A + (size_t)(b * S_LEN + m0c + row) * 1024 + kk + c8);
            async16((char*)Bs[buf] + (size_t)ci * 16,
                    BT + (size_t)(n0 + row) * 1024 + kk + c8);
        }
    };

    stage(0, 0);
    for (int kt = 0; kt < 16; ++kt) {
        __builtin_amdgcn_s_barrier();
        __builtin_amdgcn_sched_barrier(0);
        if (kt + 1 < 16) {
            stage(kt + 1, (kt + 1) & 1);
            asm volatile("s_waitcnt vmcnt(4)" ::: "memory");
        } else {
            asm volatile("s_waitcnt vmcnt(0)" ::: "memory");
        }
        __builtin_amdgcn_sched_barrier(0);
        __builtin_amdgcn_s_barrier();
        __builtin_amdgcn_sched_barrier(0);
        const short* Ab = As[kt & 1];
        const short* Bb = Bs[kt & 1];
#pragma unroll
        for (int ks = 0; ks < 2; ++ks) {
            v8s af[4], bfr[2];
#pragma unroll
            for (int mt = 0; mt < 4; ++mt)
                af[mt] = *(const v8s*)((char*)Ab +
                          swz(wr * 64 + mt * 16 + ql, ks * 64 + g * 16));
#pragma unroll
            for (int nt = 0; nt < 2; ++nt)
                bfr[nt] = *(const v8s*)((char*)Bb +
                          swz(wc * 32 + nt * 16 + ql, ks * 64 + g * 16));
#pragma unroll
            for (int mt = 0; mt < 4; ++mt)
#pragma unroll
                for (int nt = 0; nt < 2; ++nt)
                    acc[mt][nt] = MFMA16(af[mt], bfr[nt], acc[mt][nt]);
        }
    }

#pragma unroll
    for (int nt = 0; nt < 2; ++nt) {
        int col = n0 + wc * 32 + nt * 16 + ql;
        float bval = bias[col];
#pragma unroll
        for (int mt = 0; mt < 4; ++mt) {
#pragma unroll
            for (int r = 0; r < 4; ++r) {
                int jc = m0c + wr * 64 + mt * 16 + g * 4 + r;   // compacted row
                if (jc < nqv) {
                    int orig = idxb[jc];
                    out[(size_t)(b * S_LEN + orig) * 1024 + col] =
                        acc[mt][nt][r] + bval;
                }
            }
        }
    }
}

extern "C" void kernel_launch(void* const* d_in, const int* in_sizes, int n_in,
                              void* d_out, int out_size, void* d_ws, size_t ws_size,
                              hipStream_t stream) {
    (void)in_sizes; (void)n_in; (void)out_size; (void)ws_size;
    const float* q  = (const float*)d_in[0];
    const float* k  = (const float*)d_in[1];
    const float* v  = (const float*)d_in[2];
    const int* qmask = (const int*)d_in[3];
    const int* vmask = (const int*)d_in[4];
    const float* Wq = (const float*)d_in[5];
    const float* bq = (const float*)d_in[6];
    const float* Wk = (const float*)d_in[7];
    const float* bk = (const float*)d_in[8];
    const float* Wv = (const float*)d_in[9];
    const float* bv = (const float*)d_in[10];
    const float* Wo = (const float*)d_in[11];
    const float* bo = (const float*)d_in[12];
    float* out = (float*)d_out;

    char* ws = (char*)d_ws;
    const size_t MB = 1024 * 1024;
    short* Xq  = (short*)(ws + 0 * MB);
    short* Xk  = (short*)(ws + 16 * MB);
    short* Xv  = (short*)(ws + 32 * MB);
    short* WTq = (short*)(ws + 48 * MB);
    short* WTk = (short*)(ws + 50 * MB);
    short* WTv = (short*)(ws + 52 * MB);
    short* WTo = (short*)(ws + 54 * MB);
    short* QW  = (short*)(ws + 56 * MB);
    short* KF  = (short*)(ws + 72 * MB);
    short* VFb = (short*)(ws + 88 * MB);
    short* Ob  = (short*)(ws + 104 * MB);
    short* penC = (short*)(ws + 120 * MB);
    int* idxB  = (int*)(ws + 121 * MB);
    int* nqB   = (int*)(ws + 122 * MB);
    // split-K partials overlay dead Xq/Xk/Xv (48 MB; dead during attn):
    // accP: 64 bh * 64 chunks * 2 pieces * 2048 shorts = 33.5 MB
    short* accP = (short*)(ws + 0 * MB);
    float* mP   = (float*)(ws + 34 * MB);     // 64*64*2*32*4B = 2 MB
    float* lP   = (float*)(ws + 37 * MB);     // 2 MB

    convert_all<<<dim3(4096, 4), 256, 0, stream>>>(q, k, v, Xq, Xk, Xv, out);
    transpose_all<<<dim3(32, 32, 4), 256, 0, stream>>>(Wq, Wk, Wv, Wo,
                                                       WTq, WTk, WTv, WTo);
    build_pen<<<32, 256, 0, stream>>>(vmask, penC);
    compact_qmask<<<NB, 256, 0, stream>>>(qmask, idxB, nqB);

    proj_all<<<dim3(512, 1, 3), 512, 0, stream>>>(Xk, Xv, Xq, WTk, WTv, WTq,
                                                  bk, bv, bq, idxB, nqB,
                                                  KF, VFb, QW);
    attn_kernel<<<dim3(64, 128), 64, 0, stream>>>(QW, KF, VFb, penC, idxB, nqB,
                                                  Ob, mP, lP, accP);
    attn_combine<<<dim3(64, 64), 64, 0, stream>>>(mP, lP, accP, idxB, nqB, Ob);
    out_gemm_c<<<320, 512, 0, stream>>>(Ob, WTo, bo, idxB, nqB, out);
}

// Round 24
// 209.395 us; speedup vs baseline: 1.1501x; 1.1501x over previous
//
#include <hip/hip_runtime.h>
#include <hip/hip_bf16.h>

// ---- types ----
typedef __attribute__((ext_vector_type(8))) short v8s;   // 8 x bf16
typedef __attribute__((ext_vector_type(4))) float v4f;
typedef __attribute__((ext_vector_type(16))) float v16f; // 32x32 MFMA C/D
typedef __attribute__((ext_vector_type(4))) unsigned v4u;

#define S_LEN 2048
#define NB 4
#define NH 16
#define LOG2E 1.4426950408889634f
// Mask constant: 1.3125 * 2^40 — EXACTLY representable in bf16 AND fp32.
#define CMASK 1443109011456.0f
#define DEFER_THR 11.55f                // ~8 * log2(e)  (T13)

__device__ __forceinline__ short f2bf(float f) {
    __hip_bfloat16 h = __float2bfloat16(f);
    union { __hip_bfloat16 h; short s; } u; u.h = h; return u.s;
}

__device__ __forceinline__ unsigned cvtpk(float lo, float hi) {
    unsigned r;
    asm("v_cvt_pk_bf16_f32 %0, %1, %2" : "=v"(r) : "v"(lo), "v"(hi));
    return r;
}

// XOR swizzle for [R][128B] LDS tiles (read side); write side realized by
// pre-swizzling the gload_lds SOURCE chunk (rule #21, R8-verified involution).
__device__ __forceinline__ int swz(int row, int col) {
    return (row * 128 + col) ^ ((row & 7) << 4);
}

__device__ __forceinline__ void async16(void* lds, const void* g) {
    __builtin_amdgcn_global_load_lds(
        (const __attribute__((address_space(1))) unsigned int*)g,
        (__attribute__((address_space(3))) unsigned int*)lds, 16, 0, 0);
}

#define MFMA16(a, b, c) __builtin_amdgcn_mfma_f32_16x16x32_bf16((a), (b), (c), 0, 0, 0)
#define MFMA32(a, b, c) __builtin_amdgcn_mfma_f32_32x32x16_bf16((a), (b), (c), 0, 0, 0)

// ------- fused convert fp32->bf16 (q,k,v) + zero-fill of out (y=3) ---------
__global__ __launch_bounds__(256) void convert_all(const float* __restrict__ q,
                                                   const float* __restrict__ k,
                                                   const float* __restrict__ v,
                                                   short* __restrict__ Xq,
                                                   short* __restrict__ Xk,
                                                   short* __restrict__ Xv,
                                                   float* __restrict__ outz) {
    if (blockIdx.y == 3) {                    // zero-fill out (dead rows = 0)
        size_t i = ((size_t)blockIdx.x * 256 + threadIdx.x) * 8;
        float4 z4 = {0.f, 0.f, 0.f, 0.f};
        *(float4*)(outz + i) = z4;
        *(float4*)(outz + i + 4) = z4;
        return;
    }
    const float* in = (blockIdx.y == 0) ? q : (blockIdx.y == 1) ? k : v;
    short* out = (blockIdx.y == 0) ? Xq : (blockIdx.y == 1) ? Xk : Xv;
    size_t i = ((size_t)blockIdx.x * 256 + threadIdx.x) * 8;
    float4 a = *(const float4*)(in + i);
    float4 b = *(const float4*)(in + i + 4);
    v8s o;
    o[0] = f2bf(a.x); o[1] = f2bf(a.y); o[2] = f2bf(a.z); o[3] = f2bf(a.w);
    o[4] = f2bf(b.x); o[5] = f2bf(b.y); o[6] = f2bf(b.z); o[7] = f2bf(b.w);
    *(v8s*)(out + i) = o;
}

// ---------------- penalty column: pen[b][s] = vm ? 0 : -CMASK (bf16) -------
__global__ __launch_bounds__(256) void build_pen(const int* __restrict__ vm,
                                                 short* __restrict__ penC) {
    int i = blockIdx.x * 256 + threadIdx.x;   // 8192 total
    penC[i] = vm[i] ? (short)0 : f2bf(-CMASK);
}

// ------------- q_mask compaction: idx[b][j] = j-th live row, nq[b] ---------
__global__ __launch_bounds__(256) void compact_qmask(const int* __restrict__ qm,
                                                     int* __restrict__ idx,
                                                     int* __restrict__ nq) {
    const int b = blockIdx.x;
    const int* m = qm + b * S_LEN;
    int* ib = idx + b * S_LEN;
    __shared__ int cnt[256];
    const int t = threadIdx.x;
    int loc[8], c = 0;
#pragma unroll
    for (int i = 0; i < 8; ++i) { int s = t * 8 + i; if (m[s]) loc[c++] = s; }
    cnt[t] = c;
    __syncthreads();
    for (int d = 1; d < 256; d <<= 1) {       // Hillis-Steele inclusive scan
        int v = (t >= d) ? cnt[t - d] : 0;
        __syncthreads();
        cnt[t] += v;
        __syncthreads();
    }
    int off = cnt[t] - c;                     // exclusive prefix
    for (int i = 0; i < c; ++i) ib[off + i] = loc[i];
    if (t == 255) nq[b] = cnt[255];
}

// ---------------- fused W[K][N] fp32 -> WT[N][K] bf16 (4 weights) ----------
__global__ __launch_bounds__(256) void transpose_all(const float* __restrict__ Wq,
                                                     const float* __restrict__ Wk,
                                                     const float* __restrict__ Wv,
                                                     const float* __restrict__ Wo,
                                                     short* __restrict__ WTq,
                                                     short* __restrict__ WTk,
                                                     short* __restrict__ WTv,
                                                     short* __restrict__ WTo) {
    const int z = blockIdx.z;
    const float* W = (z == 0) ? Wq : (z == 1) ? Wk : (z == 2) ? Wv : Wo;
    short* WT = (z == 0) ? WTq : (z == 1) ? WTk : (z == 2) ? WTv : WTo;
    __shared__ float tile[32][33];
    int k0 = blockIdx.x * 32, n0 = blockIdx.y * 32;
    int tx = threadIdx.x & 31, ty = threadIdx.x >> 5;  // ty 0..7
#pragma unroll
    for (int i = 0; i < 4; ++i)
        tile[ty + i * 8][tx] = W[(size_t)(k0 + ty + i * 8) * 1024 + n0 + tx];
    __syncthreads();
#pragma unroll
    for (int i = 0; i < 4; ++i)
        WT[(size_t)(n0 + ty + i * 8) * 1024 + k0 + tx] = f2bf(tile[tx][ty + i * 8]);
}

// ---------------- unified projection GEMM: z=0 K, z=1 V, z=2 Q-compacted ---
// XCD map (T1) + LDS swizzle (G4) + fragment-major K/V (R18) + dbuf/counted
// vmcnt (R19) + 8-wave blocks (R22). Session-verified best.
__global__ __launch_bounds__(512)
void proj_all(const short* __restrict__ Xk, const short* __restrict__ Xv,
              const short* __restrict__ Xq,
              const short* __restrict__ WTk, const short* __restrict__ WTv,
              const short* __restrict__ WTq,
              const float* __restrict__ bk, const float* __restrict__ bv,
              const float* __restrict__ bq,
              const int* __restrict__ idx, const int* __restrict__ nq,
              short* __restrict__ KF, short* __restrict__ VF,
              short* __restrict__ QW) {
    __shared__ short As[2][128 * 64];
    __shared__ short Bs[2][128 * 64];
    const int tid = threadIdx.x;
    const int l = tid & 63, w = tid >> 6;       // w in 0..7
    const int g = l >> 4, ql = l & 15;
    const int z = blockIdx.z;
    const int bid = blockIdx.x;
    const int y = (bid & 7) + 8 * (bid >> 6);   // M-tile (XCD-pinned)
    const int n0 = ((bid >> 3) & 7) * 128;      // N-tile (cycles fastest)
    const int wr = w >> 2, wc = w & 3;          // 2x4 wave grid

    int b = 0, m0 = y * 128, m0c = 0, nqv = 0;
    const int* idxb = nullptr;
    if (z == 2) {
        if (y >= 36) return;
        b = y / 9; m0c = (y % 9) * 128;
        nqv = nq[b];
        if (m0c >= nqv) return;
        idxb = idx + b * S_LEN;
    }
    const short* A  = (z == 0) ? Xk : (z == 1) ? Xv : Xq;
    const short* BT = (z == 0) ? WTk : (z == 1) ? WTv : WTq;
    const float* bias = (z == 0) ? bk : (z == 1) ? bv : bq;

    // per-thread A-row (gathered for Q slice; linear otherwise): 2 per thread
    int arow[2];
#pragma unroll
    for (int i = 0; i < 2; ++i) {
        int row = (i * 512 + tid) >> 3;
        if (z == 2) {
            int jc = m0c + row;
            arow[i] = b * S_LEN + idxb[(jc < nqv) ? jc : (nqv - 1)];
        } else {
            arow[i] = m0 + row;
        }
    }
    // pre-swizzled source chunk (rule #21)
    const int c8 = (((l & 7) ^ (l >> 3))) * 8;

    v4f acc[4][2] = {};

    auto stage = [&](int kt, int buf) {
        const int kk = kt * 64;
#pragma unroll
        for (int i = 0; i < 2; ++i) {
            int ci = i * 512 + tid;
            async16((char*)As[buf] + (size_t)ci * 16,
                    A + (size_t)arow[i] * 1024 + kk + c8);
            async16((char*)Bs[buf] + (size_t)ci * 16,
                    BT + (size_t)(n0 + (ci >> 3)) * 1024 + kk + c8);
        }
    };

    stage(0, 0);
    for (int kt = 0; kt < 16; ++kt) {
        __builtin_amdgcn_s_barrier();         // B1: buf (kt+1)&1 free to write
        __builtin_amdgcn_sched_barrier(0);
        if (kt + 1 < 16) {
            stage(kt + 1, (kt + 1) & 1);
            asm volatile("s_waitcnt vmcnt(4)" ::: "memory");  // kt's loads done
        } else {
            asm volatile("s_waitcnt vmcnt(0)" ::: "memory");
        }
        __builtin_amdgcn_sched_barrier(0);
        __builtin_amdgcn_s_barrier();         // B2: buf kt&1 staged (all waves)
        __builtin_amdgcn_sched_barrier(0);    // rule #18: no ds_read hoisting
        const short* Ab = As[kt & 1];
        const short* Bb = Bs[kt & 1];
#pragma unroll
        for (int ks = 0; ks < 2; ++ks) {
            v8s af[4], bfr[2];
#pragma unroll
            for (int mt = 0; mt < 4; ++mt)
                af[mt] = *(const v8s*)((char*)Ab +
                          swz(wr * 64 + mt * 16 + ql, ks * 64 + g * 16));
#pragma unroll
            for (int nt = 0; nt < 2; ++nt)
                bfr[nt] = *(const v8s*)((char*)Bb +
                          swz(wc * 32 + nt * 16 + ql, ks * 64 + g * 16));
#pragma unroll
            for (int mt = 0; mt < 4; ++mt)
#pragma unroll
                for (int nt = 0; nt < 2; ++nt)
                    acc[mt][nt] = MFMA16(af[mt], bfr[nt], acc[mt][nt]);
        }
    }

#pragma unroll
    for (int nt = 0; nt < 2; ++nt) {
        int col = n0 + wc * 32 + nt * 16 + ql;
        float bval = bias[col];
        int hh = col >> 6, dd = col & 63;
#pragma unroll
        for (int mt = 0; mt < 4; ++mt) {
#pragma unroll
            for (int r = 0; r < 4; ++r) {
                int lrow = wr * 64 + mt * 16 + g * 4 + r;
                float vv = acc[mt][nt][r] + bval;
                if (z == 0) {
                    int gm = m0 + lrow;
                    int bb = gm >> 11, ss = gm & 2047;
                    // K fragment layout: [bh][kt][ks][row][hi][8]
                    size_t base = (size_t)(bb * NH + hh) * 131072
                                + (size_t)(ss >> 6) * 4096
                                + (dd >> 4) * 1024 + (ss & 63) * 16
                                + ((dd >> 3) & 1) * 8 + (dd & 7);
                    KF[base] = f2bf(vv);
                } else if (z == 1) {
                    int gm = m0 + lrow;
                    int bb = gm >> 11, ss = gm & 2047;
                    // V fragment layout: [bh][kt][ks][d][hi][8] (kp-split)
                    int wkp = ss & 63;
                    size_t base = (size_t)(bb * NH + hh) * 131072
                                + (size_t)(ss >> 6) * 4096
                                + (wkp >> 4) * 1024 + dd * 16
                                + ((wkp >> 3) & 1) * 8 + (wkp & 7);
                    VF[base] = f2bf(vv);
                } else {
                    int jc = m0c + lrow;                 // compacted row
                    vv *= 0.125f * LOG2E;
                    QW[((size_t)(b * NH + hh) * S_LEN + jc) * 64 + dd] = f2bf(vv);
                }
            }
        }
    }
}

// ---------------- flash attention: streaming, fragment-major K/V -----------
// (R18/R22-verified best: 1-wave blocks, no LDS, no barriers, 1KB-contiguous
// fragment loads. Split-K refuted x3 — R12/R17/R23 all regressed.)
__global__ __launch_bounds__(64)
void attn_kernel(const short* __restrict__ QW, const short* __restrict__ KF,
                 const short* __restrict__ VF, const short* __restrict__ penC,
                 const int* __restrict__ idx, const int* __restrict__ nq,
                 short* __restrict__ O) {
    const int l = threadIdx.x;                // 1 wave
    const int lq = l & 31, hi = l >> 5;
    const int bh = blockIdx.x;
    const int chunk = 63 - (int)blockIdx.y;   // heavy chunks dispatch first
    const int b = bh >> 4, hd = bh & 15;

    const int nqv = nq[b];
    const int cy = chunk * 32;                // compacted base row (32/wave)
    if (cy >= nqv) return;                    // dead chunk retires instantly

    const short* Qp = QW + (size_t)bh * S_LEN * 64;
    const short* Kp = KF + (size_t)bh * 131072;
    const short* Vp = VF + (size_t)bh * 131072;
    const short* pp = penC + b * S_LEN;
    const int* idxb = idx + b * S_LEN;

    const int j = cy + lq;
    const int jj = (j < nqv) ? j : (nqv - 1);
    const int q_glob = idxb[jj];
    const int qmin = __builtin_amdgcn_readfirstlane(q_glob);

    int lastj = cy + 31; if (lastj > nqv - 1) lastj = nqv - 1;
    const int NT = (idxb[lastj] >> 6) + 1;

    // Q fragments from COMPACTED QW
    v8s qf[4];
#pragma unroll
    for (int ks = 0; ks < 4; ++ks)
        qf[ks] = *(const v8s*)(Qp + (size_t)jj * 64 + ks * 16 + hi * 8);
    v8s qf4 = {};
    qf4[0] = hi ? (short)0 : (short)0x3F80;   // bf16(1.0) at virtual k=64

    v16f accO[2] = {};
    float m_run = -INFINITY, l_run = 0.f;

    auto tile = [&](int kt, bool causal) {
        const int k0 = kt * 64;
        const short* Kt = Kp + (size_t)kt * 4096;
        const short* Vt = Vp + (size_t)kt * 4096;
        short p0 = pp[k0 + lq], p1 = pp[k0 + lq + 32];

        // K fragments: 1KB contiguous per load (fragment-major layout)
        v8s kf0[4], kf1[4];
#pragma unroll
        for (int ks = 0; ks < 4; ++ks) {
            kf0[ks] = *(const v8s*)(Kt + ks * 1024 + lq * 16 + hi * 8);
            kf1[ks] = *(const v8s*)(Kt + ks * 1024 + (lq + 32) * 16 + hi * 8);
        }
        v16f acc0 = {}, acc1 = {};
        __builtin_amdgcn_s_setprio(1);
#pragma unroll
        for (int ks = 0; ks < 4; ++ks) {
            acc0 = MFMA32(kf0[ks], qf[ks], acc0);
            acc1 = MFMA32(kf1[ks], qf[ks], acc1);
        }
        // 5th slice: v_mask penalty column (hi=0 lanes carry pen at k=64)
        v8s k4a = {}, k4b = {};
        k4a[0] = hi ? (short)0 : p0;
        k4b[0] = hi ? (short)0 : p1;
        acc0 = MFMA32(k4a, qf4, acc0);
        acc1 = MFMA32(k4b, qf4, acc1);
        __builtin_amdgcn_s_setprio(0);

        float s[32];
#pragma unroll
        for (int jn = 0; jn < 16; ++jn) { s[jn] = acc0[jn]; s[16 + jn] = acc1[jn]; }
        if (causal) {
#pragma unroll
            for (int t = 0; t < 2; ++t)
#pragma unroll
                for (int jn = 0; jn < 16; ++jn) {
                    int kp = k0 + t * 32 + (jn & 3) + 8 * (jn >> 2) + 4 * hi;
                    if (kp > q_glob) s[t * 16 + jn] -= CMASK;
                }
        }
        // tree max (depth 5)
        float t8[8];
#pragma unroll
        for (int i = 0; i < 8; ++i)
            t8[i] = fmaxf(fmaxf(s[i], s[i + 8]), fmaxf(s[i + 16], s[i + 24]));
#pragma unroll
        for (int i = 0; i < 4; ++i) t8[i] = fmaxf(t8[i], t8[i + 4]);
        float tmax = fmaxf(fmaxf(t8[0], t8[1]), fmaxf(t8[2], t8[3]));
        tmax = fmaxf(tmax, __shfl_xor(tmax, 32, 64));   // cross-half

        // T13 defer-max
        if (__any(tmax > m_run + DEFER_THR)) {
            float mnew = fmaxf(m_run, tmax);
            float scale = exp2f(m_run - mnew);
            m_run = mnew;
            l_run *= scale;
#pragma unroll
            for (int jn = 0; jn < 16; ++jn) {
                float sc = __shfl(scale, (jn & 3) + 8 * (jn >> 2) + 4 * hi, 64);
                accO[0][jn] *= sc;
                accO[1][jn] *= sc;
            }
        }
#pragma unroll
        for (int i = 0; i < 32; ++i) s[i] = exp2f(s[i] - m_run);
        // tree sum
        float u8[8];
#pragma unroll
        for (int i = 0; i < 8; ++i)
            u8[i] = (s[i] + s[i + 8]) + (s[i + 16] + s[i + 24]);
#pragma unroll
        for (int i = 0; i < 4; ++i) u8[i] += u8[i + 4];
        float psum = (u8[0] + u8[1]) + (u8[2] + u8[3]);
        psum += __shfl_xor(psum, 32, 64);               // cross-half
        l_run += psum;

        // V fragments: 1KB contiguous per load (fragment-major layout)
        v8s vf0[4], vf1[4];
#pragma unroll
        for (int ks = 0; ks < 4; ++ks) {
            vf0[ks] = *(const v8s*)(Vt + ks * 1024 + lq * 16 + hi * 8);
            vf1[ks] = *(const v8s*)(Vt + ks * 1024 + (lq + 32) * 16 + hi * 8);
        }

        // P -> PV A-operand in registers (cvt_pk + permlane32_swap; SSA-distinct)
        v8s PA[4];
#pragma unroll
        for (int t = 0; t < 2; ++t)
#pragma unroll
            for (int sf = 0; sf < 2; ++sf) {
                int base = t * 16 + sf * 8;
                unsigned x0 = cvtpk(s[base + 0], s[base + 1]);
                unsigned x1 = cvtpk(s[base + 2], s[base + 3]);
                unsigned y0 = cvtpk(s[base + 4], s[base + 5]);
                unsigned y1 = cvtpk(s[base + 6], s[base + 7]);
                asm volatile("v_permlane32_swap_b32 %0, %1" : "+v"(x0), "+v"(y0));
                asm volatile("v_permlane32_swap_b32 %0, %1" : "+v"(x1), "+v"(y1));
                v4u wv; wv[0] = x0; wv[1] = x1; wv[2] = y0; wv[3] = y1;
                union { v4u u; v8s s8; } cvt; cvt.u = wv;
                PA[t * 2 + sf] = cvt.s8;
            }

        __builtin_amdgcn_s_setprio(1);
#pragma unroll
        for (int ks = 0; ks < 4; ++ks) {
            accO[0] = MFMA32(PA[ks], vf0[ks], accO[0]);
            accO[1] = MFMA32(PA[ks], vf1[ks], accO[1]);
        }
        __builtin_amdgcn_s_setprio(0);
    };

    // main causal loop — no barriers, compiler-pipelined
    for (int kt = 0; kt < NT; ++kt)
        tile(kt, kt * 64 + 63 > qmin);

    // Rescue (per-wave): rows whose causal-valid keys are ALL masked tie
    // with future keys at exactly -CMASK (fp32 reference semantics).
    int kt = NT;
    while (kt < 32 && __any(m_run < -1e11f)) {
        tile(kt, true);
        ++kt;
    }

    // epilogue: write Ob at COMPACTED row (dense for out_gemm_c)
    float inv = 1.0f / l_run;
#pragma unroll
    for (int jn = 0; jn < 16; ++jn) {
        int rowq = (jn & 3) + 8 * (jn >> 2) + 4 * hi;
        float iv = __shfl(inv, rowq, 64);
        int jrow = cy + rowq;                          // compacted row
        if (jrow < nqv) {
            size_t base = (size_t)(b * S_LEN + jrow) * 1024 + hd * 64 + lq;
            O[base]      = f2bf(accO[0][jn] * iv);
            O[base + 32] = f2bf(accO[1][jn] * iv);
        }
    }
}

// ---------------- output projection, q-compacted (scatter + bias) ----------
// Same XCD map + dbuf/counted-vmcnt; 8-wave blocks (R22).
__global__ __launch_bounds__(512)
void out_gemm_c(const short* __restrict__ A, const short* __restrict__ BT,
                const float* __restrict__ bias, const int* __restrict__ idx,
                const int* __restrict__ nq, float* __restrict__ out) {
    __shared__ short As[2][128 * 64];
    __shared__ short Bs[2][128 * 64];
    const int tid = threadIdx.x;
    const int l = tid & 63, w = tid >> 6;       // w in 0..7
    const int g = l >> 4, ql = l & 15;
    const int bid = blockIdx.x;
    const int y = (bid & 7) + 8 * (bid >> 6);   // M-tile (XCD-pinned)
    if (y >= 36) return;
    const int n0 = ((bid >> 3) & 7) * 128;      // N-tile (cycles fastest)
    const int b = y / 9;
    const int m0c = (y % 9) * 128;
    const int nqv = nq[b];
    if (m0c >= nqv) return;
    const int* idxb = idx + b * S_LEN;
    const int wr = w >> 2, wc = w & 3;          // 2x4 wave grid
    const int c8 = (((l & 7) ^ (l >> 3))) * 8;  // pre-swizzled source chunk

    v4f acc[4][2] = {};

    auto stage = [&](int kt, int buf) {
        const int kk = kt * 64;
#pragma unroll
        for (int i = 0; i < 2; ++i) {
            int ci = i * 512 + tid;
            int row = ci >> 3;
            async16((char*)As[buf] + (size_t)ci * 16,
                    A + (size_t)(b * S_LEN + m0c + row) * 1024 + kk + c8);
            async16((char*)Bs[buf] + (size_t)ci * 16,
                    BT + (size_t)(n0 + row) * 1024 + kk + c8);
        }
    };

    stage(0, 0);
    for (int kt = 0; kt < 16; ++kt) {
        __builtin_amdgcn_s_barrier();         // B1: buf (kt+1)&1 free to write
        __builtin_amdgcn_sched_barrier(0);
        if (kt + 1 < 16) {
            stage(kt + 1, (kt + 1) & 1);
            asm volatile("s_waitcnt vmcnt(4)" ::: "memory");  // kt's loads done
        } else {
            asm volatile("s_waitcnt vmcnt(0)" ::: "memory");
        }
        __builtin_amdgcn_sched_barrier(0);
        __builtin_amdgcn_s_barrier();         // B2: buf kt&1 staged (all waves)
        __builtin_amdgcn_sched_barrier(0);    // rule #18: no ds_read hoisting
        const short* Ab = As[kt & 1];
        const short* Bb = Bs[kt & 1];
#pragma unroll
        for (int ks = 0; ks < 2; ++ks) {
            v8s af[4], bfr[2];
#pragma unroll
            for (int mt = 0; mt < 4; ++mt)
                af[mt] = *(const v8s*)((char*)Ab +
                          swz(wr * 64 + mt * 16 + ql, ks * 64 + g * 16));
#pragma unroll
            for (int nt = 0; nt < 2; ++nt)
                bfr[nt] = *(const v8s*)((char*)Bb +
                          swz(wc * 32 + nt * 16 + ql, ks * 64 + g * 16));
#pragma unroll
            for (int mt = 0; mt < 4; ++mt)
#pragma unroll
                for (int nt = 0; nt < 2; ++nt)
                    acc[mt][nt] = MFMA16(af[mt], bfr[nt], acc[mt][nt]);
        }
    }

#pragma unroll
    for (int nt = 0; nt < 2; ++nt) {
        int col = n0 + wc * 32 + nt * 16 + ql;
        float bval = bias[col];
#pragma unroll
        for (int mt = 0; mt < 4; ++mt) {
#pragma unroll
            for (int r = 0; r < 4; ++r) {
                int jc = m0c + wr * 64 + mt * 16 + g * 4 + r;   // compacted row
                if (jc < nqv) {
                    int orig = idxb[jc];
                    out[(size_t)(b * S_LEN + orig) * 1024 + col] =
                        acc[mt][nt][r] + bval;
                }
            }
        }
    }
}

extern "C" void kernel_launch(void* const* d_in, const int* in_sizes, int n_in,
                              void* d_out, int out_size, void* d_ws, size_t ws_size,
                              hipStream_t stream) {
    (void)in_sizes; (void)n_in; (void)out_size; (void)ws_size;
    const float* q  = (const float*)d_in[0];
    const float* k  = (const float*)d_in[1];
    const float* v  = (const float*)d_in[2];
    const int* qmask = (const int*)d_in[3];
    const int* vmask = (const int*)d_in[4];
    const float* Wq = (const float*)d_in[5];
    const float* bq = (const float*)d_in[6];
    const float* Wk = (const float*)d_in[7];
    const float* bk = (const float*)d_in[8];
    const float* Wv = (const float*)d_in[9];
    const float* bv = (const float*)d_in[10];
    const float* Wo = (const float*)d_in[11];
    const float* bo = (const float*)d_in[12];
    float* out = (float*)d_out;

    char* ws = (char*)d_ws;
    const size_t MB = 1024 * 1024;
    short* Xq  = (short*)(ws + 0 * MB);
    short* Xk  = (short*)(ws + 16 * MB);
    short* Xv  = (short*)(ws + 32 * MB);
    short* WTq = (short*)(ws + 48 * MB);
    short* WTk = (short*)(ws + 50 * MB);
    short* WTv = (short*)(ws + 52 * MB);
    short* WTo = (short*)(ws + 54 * MB);
    short* QW  = (short*)(ws + 56 * MB);
    short* KF  = (short*)(ws + 72 * MB);
    short* VFb = (short*)(ws + 88 * MB);
    short* Ob  = (short*)(ws + 104 * MB);
    short* penC = (short*)(ws + 120 * MB);
    int* idxB  = (int*)(ws + 121 * MB);
    int* nqB   = (int*)(ws + 122 * MB);

    convert_all<<<dim3(4096, 4), 256, 0, stream>>>(q, k, v, Xq, Xk, Xv, out);
    transpose_all<<<dim3(32, 32, 4), 256, 0, stream>>>(Wq, Wk, Wv, Wo,
                                                       WTq, WTk, WTv, WTo);
    build_pen<<<32, 256, 0, stream>>>(vmask, penC);
    compact_qmask<<<NB, 256, 0, stream>>>(qmask, idxB, nqB);

    proj_all<<<dim3(512, 1, 3), 512, 0, stream>>>(Xk, Xv, Xq, WTk, WTv, WTq,
                                                  bk, bv, bq, idxB, nqB,
                                                  KF, VFb, QW);
    attn_kernel<<<dim3(64, 64), 64, 0, stream>>>(QW, KF, VFb, penC, idxB, nqB, Ob);
    out_gemm_c<<<320, 512, 0, stream>>>(Ob, WTo, bo, idxB, nqB, out);
}